// Round 1
// baseline (385.655 us; speedup 1.0000x reference)
//
#include <hip/hip_runtime.h>

// PackedAvgPool1d over ragged packed sequences (K=2, S=2 in the bench; code is
// generic in K,S for batch <= 64).
//
// v2: multi-row blocks. One block per ROWS(=8) consecutive output rows
// (grid = ceil(total_y/8) = 5056, block = 192 threads = 768/4 float4 lanes).
// Wave 0 computes the ragged prefix scan ONCE per block (6-step shfl_up over
// 64 lanes; seq_lens is 128 B, L2-hot), then resolves all 8 rows' owning
// sequence with one ballot+popcount each, broadcasting {x_base, window start,
// seq_len} through LDS arrays. One barrier per block instead of one per row.
//
// K==2 fast path is fully unrolled: each thread issues 16 independent float4
// loads (2 taps x 8 rows) before any use -> deep memory-level parallelism.
// All global traffic streams coalesced; each input row is read exactly once
// (K==S), each output row written once -> ~373 MB total, HBM-bound.
// Invalid taps clamp to pos L-1 (same cache lines as valid taps -> L1 hit)
// and are masked by a 0/1 multiplier, matching the reference masked average.

#define DIM  768
#define D4   (DIM / 4)   // 192 float4 per row
#define ROWS 8           // output rows per block

// clang-native vector for __builtin_nontemporal_store (HIP float4 is a class)
typedef float vfloat4 __attribute__((ext_vector_type(4)));

__global__ __launch_bounds__(D4) void packed_avgpool_rows(
    const float4* __restrict__ x,
    const int*    __restrict__ seq_lens,
    const int*    __restrict__ kptr,
    const int*    __restrict__ sptr,
    float4*       __restrict__ out,
    int batch, int total_y)
{
    __shared__ int s_base[ROWS];  // x_cu[b]  (token offset of owning sequence)
    __shared__ int s_p0[ROWS];    // j * S    (window start within the sequence)
    __shared__ int s_L[ROWS];     // seq_lens[b]; 0 => row out of range (skip)
    __shared__ int s_K;

    const int row0 = blockIdx.x * ROWS;

    if (threadIdx.x < 64) {              // wave 0 only (batch <= 64)
        const int lane = threadIdx.x;
        const int K = kptr[0];
        const int S = sptr[0];
        int L = (lane < batch) ? seq_lens[lane] : 0;
        int over = (L > K) ? (L - K) : 0;
        int yl   = (L == 0) ? 0 : (over + S - 1) / S + 1;  // ceil_div(max(L-K,0),S)+1

        // inclusive prefix scan over 64 lanes (tokens xs, output rows ys)
        int xs = L, ys = yl;
        #pragma unroll
        for (int off = 1; off < 64; off <<= 1) {
            int xv = __shfl_up(xs, off);
            int yv = __shfl_up(ys, off);
            if (lane >= off) { xs += xv; ys += yv; }
        }

        if (lane == 0) s_K = K;

        // resolve all ROWS rows against the in-register scan
        #pragma unroll
        for (int r = 0; r < ROWS; ++r) {
            const int row = row0 + r;
            // owning sequence: b = #{t : inclusive_ys[t] <= row}
            unsigned long long bal = __ballot(ys <= row);
            int b   = (int)__popcll(bal);
            // row < total_y guarantees b <= batch-1 (last seq's inclusive ys
            // = total_y > row); out-of-range rows are masked via s_L = 0.
            int xcu = (b == 0) ? 0 : __shfl(xs, b - 1);   // exclusive prefixes
            int ycu = (b == 0) ? 0 : __shfl(ys, b - 1);
            int Lb  = __shfl(L, b & 63);
            if (lane == 0) {
                s_base[r] = xcu;
                s_p0[r]   = (row - ycu) * S;
                s_L[r]    = (row < total_y) ? Lb : 0;
            }
        }
    }
    __syncthreads();

    const int K   = s_K;
    const int col = threadIdx.x;

    if (K == 2) {
        // fast path (bench config): fully unrolled, 16 independent loads in
        // flight per thread before any consumer.
        #pragma unroll
        for (int r = 0; r < ROWS; ++r) {
            const int L = s_L[r];                 // wave-uniform
            if (L == 0) continue;
            const int base = s_base[r];
            const int p0   = s_p0[r];

            const int  p1    = p0 + 1;
            const int  c1    = (p1 < L) ? p1 : (L - 1);   // clamp: dup line, L1 hit
            const float m1   = (p1 < L) ? 1.f : 0.f;

            float4 v0 = x[(base + p0) * D4 + col];        // p0 always valid
            float4 v1 = x[(base + c1) * D4 + col];

            const float inv = 1.0f / (1.0f + m1);         // cnt in {1,2}: exact
            vfloat4 rv = { (v0.x + m1 * v1.x) * inv,
                           (v0.y + m1 * v1.y) * inv,
                           (v0.z + m1 * v1.z) * inv,
                           (v0.w + m1 * v1.w) * inv };
            __builtin_nontemporal_store(
                rv, (vfloat4*)&out[(row0 + r) * D4 + col]);
        }
    } else {
        // generic K,S path
        #pragma unroll
        for (int r = 0; r < ROWS; ++r) {
            const int L = s_L[r];
            if (L == 0) continue;
            const int base = s_base[r];
            const int p0   = s_p0[r];

            float4 acc = make_float4(0.f, 0.f, 0.f, 0.f);
            float  cnt = 0.f;
            for (int k = 0; k < K; ++k) {
                int   pos  = p0 + k;
                int   cpos = (pos < L) ? pos : (L - 1);
                float m    = (pos < L) ? 1.f : 0.f;
                float4 v = x[(base + cpos) * D4 + col];
                acc.x += m * v.x; acc.y += m * v.y;
                acc.z += m * v.z; acc.w += m * v.w;
                cnt   += m;
            }
            const float inv = 1.0f / cnt;
            vfloat4 rv = { acc.x * inv, acc.y * inv, acc.z * inv, acc.w * inv };
            __builtin_nontemporal_store(
                rv, (vfloat4*)&out[(row0 + r) * D4 + col]);
        }
    }
}

extern "C" void kernel_launch(void* const* d_in, const int* in_sizes, int n_in,
                              void* d_out, int out_size, void* d_ws, size_t ws_size,
                              hipStream_t stream) {
    const float4* x        = (const float4*)d_in[0];
    const int*    seq_lens = (const int*)d_in[1];
    const int*    kptr     = (const int*)d_in[2];
    const int*    sptr     = (const int*)d_in[3];
    float4*       out      = (float4*)d_out;

    const int batch   = in_sizes[1];
    const int total_y = out_size / DIM;
    const int nblocks = (total_y + ROWS - 1) / ROWS;

    packed_avgpool_rows<<<nblocks, D4, 0, stream>>>(
        x, seq_lens, kptr, sptr, out, batch, total_y);
}

// Round 2
// 354.215 us; speedup vs baseline: 1.0888x; 1.0888x over previous
//
#include <hip/hip_runtime.h>

// PackedAvgPool1d over ragged packed sequences (K=2, S=2 in the bench; code is
// generic in K,S for batch <= 64).
//
// v3: wave-autonomous persistent kernel. Every 64-lane wave independently
// recomputes the ragged prefix scan in registers (seq_lens is 128 B, L1-hot,
// 6-step shfl_up), then grid-strides over output rows. Per row the descriptor
// is one ballot+popcount + 3 shfls -- NO LDS, NO barriers anywhere.
//
// Each wave owns a whole output row: 3 column chunks (192 float4 / 64 lanes)
// x K=2 taps = 6 independent 1 KB coalesced loads issued before any use
// (deep MLP per wave). Grid = min(ceil(total_y/4), 2048) blocks x 256 threads
// = up to 8192 waves (full 32-wave/CU residency on 256 CUs), ~5 rows/wave so
// the scan amortizes.
//
// All global traffic streams exactly once (K==S): read 248.5 MB, write
// 124.3 MB -> ~373 MB, HBM-bound (~60 us floor at 6.3 TB/s). Nontemporal
// loads/stores keep the read-once/write-once streams out of L2's way.
// Invalid taps clamp to pos L-1 (same cache line as a valid tap) and are
// masked by a 0/1 multiplier, matching the reference's masked average.

#define DIM 768
#define D4  (DIM / 4)   // 192 float4 per row
#define WPB 4           // waves per block
#define BLOCK (WPB * 64)

// clang-native vector type: supports elementwise ops, scalar broadcast, and
// __builtin_nontemporal_{load,store} (HIP float4 is a class; builtins choke).
typedef float vfloat4 __attribute__((ext_vector_type(4)));

__global__ __launch_bounds__(BLOCK) void packed_avgpool_waves(
    const vfloat4* __restrict__ x,
    const int*     __restrict__ seq_lens,
    const int*     __restrict__ kptr,
    const int*     __restrict__ sptr,
    vfloat4*       __restrict__ out,
    int batch, int total_y, int nwaves)
{
    const int lane = threadIdx.x & 63;
    const int wid  = blockIdx.x * WPB + (threadIdx.x >> 6);

    const int K = kptr[0];
    const int S = sptr[0];

    // per-wave ragged scan, entirely in registers (batch <= 64)
    int L    = (lane < batch) ? seq_lens[lane] : 0;
    int over = (L > K) ? (L - K) : 0;
    int yl   = (L == 0) ? 0 : (over + S - 1) / S + 1;  // ceil_div(max(L-K,0),S)+1

    int xs = L, ys = yl;   // inclusive prefix sums (tokens, output rows)
    #pragma unroll
    for (int off = 1; off < 64; off <<= 1) {
        int xv = __shfl_up(xs, off);
        int yv = __shfl_up(ys, off);
        if (lane >= off) { xs += xv; ys += yv; }
    }

    if (K == 2) {
        // fast path (bench config)
        for (int row = wid; row < total_y; row += nwaves) {
            // owning sequence: b = #{t : inclusive_ys[t] <= row}  (<= batch-1)
            unsigned long long bal = __ballot(ys <= row);
            int b   = (int)__popcll(bal) & 63;
            int ib  = (b > 0) ? (b - 1) : 0;
            int xcu = __shfl(xs, ib);  if (b == 0) xcu = 0;  // exclusive prefixes
            int ycu = __shfl(ys, ib);  if (b == 0) ycu = 0;
            int Lb  = __shfl(L, b);

            const int   p0 = (row - ycu) * S;
            const int   p1 = p0 + 1;
            const int   c1 = (p1 < Lb) ? p1 : (Lb - 1);   // clamp: dup line, cache hit
            const float m1 = (p1 < Lb) ? 1.f : 0.f;

            const vfloat4* r0 = x + (long long)(xcu + p0) * D4;
            const vfloat4* r1 = x + (long long)(xcu + c1) * D4;

            // 6 independent coalesced loads in flight before any consumer
            vfloat4 a0 = __builtin_nontemporal_load(r0 + lane);
            vfloat4 a1 = __builtin_nontemporal_load(r0 + lane + 64);
            vfloat4 a2 = __builtin_nontemporal_load(r0 + lane + 128);
            vfloat4 b0 = __builtin_nontemporal_load(r1 + lane);
            vfloat4 b1 = __builtin_nontemporal_load(r1 + lane + 64);
            vfloat4 b2 = __builtin_nontemporal_load(r1 + lane + 128);

            const float inv = 1.0f / (1.0f + m1);         // cnt in {1,2}: exact
            vfloat4* o = out + (long long)row * D4;
            __builtin_nontemporal_store((a0 + m1 * b0) * inv, o + lane);
            __builtin_nontemporal_store((a1 + m1 * b1) * inv, o + lane + 64);
            __builtin_nontemporal_store((a2 + m1 * b2) * inv, o + lane + 128);
        }
    } else {
        // generic K,S path
        for (int row = wid; row < total_y; row += nwaves) {
            unsigned long long bal = __ballot(ys <= row);
            int b   = (int)__popcll(bal) & 63;
            int ib  = (b > 0) ? (b - 1) : 0;
            int xcu = __shfl(xs, ib);  if (b == 0) xcu = 0;
            int ycu = __shfl(ys, ib);  if (b == 0) ycu = 0;
            int Lb  = __shfl(L, b);

            const int p0 = (row - ycu) * S;

            vfloat4 acc0 = 0.f, acc1 = 0.f, acc2 = 0.f;
            float   cnt  = 0.f;
            for (int k = 0; k < K; ++k) {
                int   pos  = p0 + k;
                int   cpos = (pos < Lb) ? pos : (Lb - 1);
                float m    = (pos < Lb) ? 1.f : 0.f;
                const vfloat4* r = x + (long long)(xcu + cpos) * D4;
                acc0 += m * __builtin_nontemporal_load(r + lane);
                acc1 += m * __builtin_nontemporal_load(r + lane + 64);
                acc2 += m * __builtin_nontemporal_load(r + lane + 128);
                cnt  += m;
            }
            const float inv = 1.0f / cnt;
            vfloat4* o = out + (long long)row * D4;
            __builtin_nontemporal_store(acc0 * inv, o + lane);
            __builtin_nontemporal_store(acc1 * inv, o + lane + 64);
            __builtin_nontemporal_store(acc2 * inv, o + lane + 128);
        }
    }
}

extern "C" void kernel_launch(void* const* d_in, const int* in_sizes, int n_in,
                              void* d_out, int out_size, void* d_ws, size_t ws_size,
                              hipStream_t stream) {
    const vfloat4* x        = (const vfloat4*)d_in[0];
    const int*     seq_lens = (const int*)d_in[1];
    const int*     kptr     = (const int*)d_in[2];
    const int*     sptr     = (const int*)d_in[3];
    vfloat4*       out      = (vfloat4*)d_out;

    const int batch   = in_sizes[1];
    const int total_y = out_size / DIM;

    // one wave per row per pass; cap grid for full residency + grid-stride
    int nblocks = (total_y + WPB - 1) / WPB;
    if (nblocks > 2048) nblocks = 2048;
    const int nwaves = nblocks * WPB;

    packed_avgpool_waves<<<nblocks, BLOCK, 0, stream>>>(
        x, seq_lens, kptr, sptr, out, batch, total_y, nwaves);
}